// Round 3
// baseline (436.136 us; speedup 1.0000x reference)
//
#include <hip/hip_runtime.h>
#include <hip/hip_bf16.h>
#include <cstdint>
#include <cstddef>

#define B_ 2
#define T_ 2048
#define C_ 1024
#define H_ 16
#define D_ 64
#define BT_ (B_*T_)
#define QKV_S 3072

typedef __bf16 bf16;
typedef __bf16 bf16x4 __attribute__((ext_vector_type(4)));
typedef __bf16 bf16x8 __attribute__((ext_vector_type(8)));
typedef float f32x4 __attribute__((ext_vector_type(4)));

// ---------------------------------------------------------------- cast f32->bf16
__global__ __launch_bounds__(256) void cast_f32_bf16(const float* __restrict__ in,
                                                     bf16* __restrict__ out, int n) {
  int stride = gridDim.x * blockDim.x;
  for (int i = blockIdx.x * blockDim.x + threadIdx.x; i * 4 < n; i += stride) {
    float4 v = *reinterpret_cast<const float4*>(in + (size_t)i * 4);
    bf16x4 o;
    o[0] = (bf16)v.x; o[1] = (bf16)v.y; o[2] = (bf16)v.z; o[3] = (bf16)v.w;
    *reinterpret_cast<bf16x4*>(out + (size_t)i * 4) = o;
  }
}

// ---------------------------------------------------------------- GEMM: C = A @ B^T + bias
// A [M,K] bf16 row-major, Bm [N,K] bf16 row-major, bias [N] f32.
// 128x128 tile, BK=32, 256 threads = 4 waves (2x2), each wave 64x64 = 4x4 frags.
template<typename OutT>
__global__ __launch_bounds__(256) void gemm_bt(const bf16* __restrict__ A,
                                               const bf16* __restrict__ Bm,
                                               const float* __restrict__ bias,
                                               OutT* __restrict__ Cout,
                                               int M, int N, int K) {
  __shared__ bf16 As[128 * 32];
  __shared__ bf16 Bs[128 * 32];
  const int tid = threadIdx.x;
  const int wid = tid >> 6, lane = tid & 63;
  const int grp = lane >> 4, li = lane & 15;
  const int wr = wid >> 1, wc = wid & 1;
  const int m0 = blockIdx.y * 128, n0 = blockIdx.x * 128;

  f32x4 acc[4][4] = {};

  const int srow = lane >> 2;         // 0..15
  const int scol = (lane & 3) * 8;    // 0,8,16,24

  for (int k0 = 0; k0 < K; k0 += 32) {
#pragma unroll
    for (int p = 0; p < 2; ++p) {
      const int rbase = (p * 4 + wid) * 16;
      const bf16* ga = A + (size_t)(m0 + rbase + srow) * K + (k0 + scol);
      const bf16* gb = Bm + (size_t)(n0 + rbase + srow) * K + (k0 + scol);
      bf16* la = As + (p * 4 + wid) * 512;
      bf16* lb = Bs + (p * 4 + wid) * 512;
      __builtin_amdgcn_global_load_lds((__attribute__((address_space(1))) void*)ga,
                                       (__attribute__((address_space(3))) void*)la, 16, 0, 0);
      __builtin_amdgcn_global_load_lds((__attribute__((address_space(1))) void*)gb,
                                       (__attribute__((address_space(3))) void*)lb, 16, 0, 0);
    }
    __syncthreads();

    bf16x8 af[4], bfr[4];
#pragma unroll
    for (int m = 0; m < 4; ++m)
      af[m] = *reinterpret_cast<const bf16x8*>(&As[(wr * 64 + m * 16 + li) * 32 + grp * 8]);
#pragma unroll
    for (int n = 0; n < 4; ++n)
      bfr[n] = *reinterpret_cast<const bf16x8*>(&Bs[(wc * 64 + n * 16 + li) * 32 + grp * 8]);
#pragma unroll
    for (int m = 0; m < 4; ++m)
#pragma unroll
      for (int n = 0; n < 4; ++n)
        acc[m][n] = __builtin_amdgcn_mfma_f32_16x16x32_bf16(af[m], bfr[n], acc[m][n], 0, 0, 0);
    __syncthreads();
  }

  float bcol[4];
#pragma unroll
  for (int n = 0; n < 4; ++n) bcol[n] = bias[n0 + wc * 64 + n * 16 + li];
#pragma unroll
  for (int m = 0; m < 4; ++m) {
#pragma unroll
    for (int n = 0; n < 4; ++n) {
      const int col = n0 + wc * 64 + n * 16 + li;
#pragma unroll
      for (int j = 0; j < 4; ++j) {
        const int row = m0 + wr * 64 + m * 16 + grp * 4 + j;
        float v = acc[m][n][j] + bcol[n];
        Cout[(size_t)row * N + col] = (OutT)v;
      }
    }
  }
}

// ---------------------------------------------------------------- V transpose: qkv v-part -> Vt[bh][d][T]
__global__ __launch_bounds__(256) void transpose_v(const bf16* __restrict__ qkv,
                                                   bf16* __restrict__ Vt) {
  __shared__ bf16 tile[64 * 72];
  const int tid = threadIdx.x;
  const int t0 = blockIdx.x * 64, bh = blockIdx.y;
  const int b = bh >> 4, h = bh & 15;
#pragma unroll
  for (int p = 0; p < 2; ++p) {
    int idx = p * 256 + tid;
    int r = idx >> 3, c = (idx & 7) * 8;
    bf16x8 v = *reinterpret_cast<const bf16x8*>(qkv + (size_t)(b * T_ + t0 + r) * QKV_S + 2 * C_ + h * D_ + c);
    *reinterpret_cast<bf16x8*>(&tile[r * 72 + c]) = v;
  }
  __syncthreads();
#pragma unroll
  for (int p = 0; p < 2; ++p) {
    int idx = p * 256 + tid;
    int d = idx >> 3, tc = (idx & 7) * 8;
    bf16x8 o;
#pragma unroll
    for (int j = 0; j < 8; ++j) o[j] = tile[(tc + j) * 72 + d];
    *reinterpret_cast<bf16x8*>(Vt + ((size_t)bh * D_ + d) * T_ + t0 + tc) = o;
  }
}

// ---------------------------------------------------------------- flash attention w/ ALiBi (swapped operands)
// qkv: [B*T,3072] bf16 (q at h*64, k at 1024+h*64). Vt: [B*H,64,T] bf16. Y: [B*T,1024] bf16.
// Grid (T/64, B*H), block 256 = 4 independent waves (no __syncthreads).
// S^T = mfma(K,Q): lane li owns q-row (q0+wid*16+li); regs hold kv = n*16+grp*4+j.
// O^T = mfma(Vt,P): lane li keeps q-row ownership; epilogue transposes via LDS.
__global__ __launch_bounds__(256) void attn_kernel(const bf16* __restrict__ qkv,
                                                   const bf16* __restrict__ Vt,
                                                   bf16* __restrict__ Y) {
  __shared__ bf16 Ps[4 * 16 * 72];   // per-wave [16 q][72] padded relayout buffer
  const int tid = threadIdx.x;
  const int wid = tid >> 6, lane = tid & 63;
  const int grp = lane >> 4, li = lane & 15;
  const int qt = gridDim.x - 1 - blockIdx.x;   // heavy blocks first
  const int bh = blockIdx.y;
  const int b = bh >> 4, h = bh & 15;
  const int q0 = qt * 64;
  const int qi = q0 + wid * 16 + li;           // this lane's q row
  const float slope = exp2f(-0.5f * (float)(h + 1));

  bf16* Pw = Ps + wid * (16 * 72);

  // Q fragments (B-operand: row=li<->q, k=d), pre-scaled by 1/sqrt(64)=0.125 (exact in bf16)
  bf16x8 qf[2];
  {
    const bf16* qrow = qkv + (size_t)(b * T_ + qi) * QKV_S + h * D_;
    qf[0] = *reinterpret_cast<const bf16x8*>(qrow + grp * 8);
    qf[1] = *reinterpret_cast<const bf16x8*>(qrow + 32 + grp * 8);
#pragma unroll
    for (int c = 0; c < 2; ++c)
#pragma unroll
      for (int j = 0; j < 8; ++j)
        qf[c][j] = (bf16)((float)qf[c][j] * 0.125f);
  }

  f32x4 oacc[4] = {};      // O^T: [d = nd*16+grp*4+j][q = li]
  float mrun = -1e30f, lrun = 0.f;

  const bf16* Kbase = qkv + (size_t)b * T_ * QKV_S + C_ + (size_t)h * D_;
  const bf16* Vbase = Vt + (size_t)bh * D_ * T_;

  auto tile = [&](int kv0, bool masked) __attribute__((always_inline)) {
    // K frags (A-operand: row=kv-local=li, k=d) and Vt frags (A-operand: row=d-local=li, k=kv)
    bf16x8 kr[4][2], vr[4][2];
#pragma unroll
    for (int n = 0; n < 4; ++n)
#pragma unroll
      for (int c = 0; c < 2; ++c)
        kr[n][c] = *reinterpret_cast<const bf16x8*>(
            Kbase + (size_t)(kv0 + n * 16 + li) * QKV_S + c * 32 + grp * 8);
#pragma unroll
    for (int nd = 0; nd < 4; ++nd)
#pragma unroll
      for (int kc = 0; kc < 2; ++kc)
        vr[nd][kc] = *reinterpret_cast<const bf16x8*>(
            Vbase + (size_t)(nd * 16 + li) * T_ + kv0 + kc * 32 + grp * 8);

    // S^T = K @ Q^T
    f32x4 s[4] = {};
#pragma unroll
    for (int n = 0; n < 4; ++n) {
      s[n] = __builtin_amdgcn_mfma_f32_16x16x32_bf16(kr[n][0], qf[0], s[n], 0, 0, 0);
      s[n] = __builtin_amdgcn_mfma_f32_16x16x32_bf16(kr[n][1], qf[1], s[n], 0, 0, 0);
    }

    // lane-local softmax over the 16 kv regs; cross-grp reduce = 2 shuffles
    float p[4][4];
    float rm = -1e30f;
#pragma unroll
    for (int n = 0; n < 4; ++n)
#pragma unroll
      for (int j = 0; j < 4; ++j) {
        const int kv = kv0 + n * 16 + grp * 4 + j;
        float sv = fmaf(-slope, (float)(qi - kv), s[n][j]);
        if (masked) sv = (kv <= qi) ? sv : -1e30f;
        p[n][j] = sv;
        rm = fmaxf(rm, sv);
      }
    rm = fmaxf(rm, __shfl_xor(rm, 16, 64));
    rm = fmaxf(rm, __shfl_xor(rm, 32, 64));
    const float mnew = fmaxf(mrun, rm);
    const float alpha = __expf(mrun - mnew);
    mrun = mnew;
    float rs = 0.f;
#pragma unroll
    for (int n = 0; n < 4; ++n)
#pragma unroll
      for (int j = 0; j < 4; ++j) {
        float e = __expf(p[n][j] - mnew);
        p[n][j] = e;
        rs += e;
      }
    rs += __shfl_xor(rs, 16, 64);
    rs += __shfl_xor(rs, 32, 64);
    lrun = lrun * alpha + rs;
#pragma unroll
    for (int nd = 0; nd < 4; ++nd)
#pragma unroll
      for (int j = 0; j < 4; ++j)
        oacc[nd][j] *= alpha;

    // P relayout: (lane li, regs kv=n*16+grp*4+j) -> B-operand rows via per-wave LDS
#pragma unroll
    for (int n = 0; n < 4; ++n) {
      bf16x4 p4;
#pragma unroll
      for (int j = 0; j < 4; ++j) p4[j] = (bf16)p[n][j];
      *reinterpret_cast<bf16x4*>(Pw + li * 72 + n * 16 + grp * 4) = p4;
    }
    asm volatile("s_waitcnt lgkmcnt(0)" ::: "memory");
    __builtin_amdgcn_sched_barrier(0);

    // O^T += Vt-tile @ P^T
#pragma unroll
    for (int kc = 0; kc < 2; ++kc) {
      bf16x8 pb = *reinterpret_cast<const bf16x8*>(Pw + li * 72 + kc * 32 + grp * 8);
#pragma unroll
      for (int nd = 0; nd < 4; ++nd)
        oacc[nd] = __builtin_amdgcn_mfma_f32_16x16x32_bf16(vr[nd][kc], pb, oacc[nd], 0, 0, 0);
    }
  };

  for (int kv0 = 0; kv0 < q0; kv0 += 64) tile(kv0, false);
  tile(q0, true);

  // epilogue: O^T/l -> transpose via Pw -> Y rows (coalesced 16B)
  const float rinv = 1.f / lrun;
  asm volatile("s_waitcnt lgkmcnt(0)" ::: "memory");
  __builtin_amdgcn_sched_barrier(0);
#pragma unroll
  for (int nd = 0; nd < 4; ++nd) {
    bf16x4 o4;
#pragma unroll
    for (int j = 0; j < 4; ++j) o4[j] = (bf16)(oacc[nd][j] * rinv);
    *reinterpret_cast<bf16x4*>(Pw + li * 72 + nd * 16 + grp * 4) = o4;
  }
  asm volatile("s_waitcnt lgkmcnt(0)" ::: "memory");
  __builtin_amdgcn_sched_barrier(0);
  {
    bf16* yrow = Y + (size_t)(b * T_ + qi) * C_ + h * D_;
#pragma unroll
    for (int c = 0; c < 2; ++c) {
      bf16x8 y8 = *reinterpret_cast<const bf16x8*>(Pw + li * 72 + (c * 4 + grp) * 8);
      *reinterpret_cast<bf16x8*>(yrow + (c * 4 + grp) * 8) = y8;
    }
  }
}

// ---------------------------------------------------------------- launch
extern "C" void kernel_launch(void* const* d_in, const int* in_sizes, int n_in,
                              void* d_out, int out_size, void* d_ws, size_t ws_size,
                              hipStream_t stream) {
  const float* x  = (const float*)d_in[0];
  const float* Wq = (const float*)d_in[1];
  const float* bq = (const float*)d_in[2];
  const float* Wk = (const float*)d_in[3];
  const float* bk = (const float*)d_in[4];
  const float* Wv = (const float*)d_in[5];
  const float* bv = (const float*)d_in[6];
  const float* Wo = (const float*)d_in[7];
  const float* bo = (const float*)d_in[8];
  float* out = (float*)d_out;

  char* ws = (char*)d_ws;
  bf16* xb    = (bf16*)ws; ws += (size_t)BT_ * C_ * 2;          // 8 MB (reused as yb)
  bf16* wqkvb = (bf16*)ws; ws += (size_t)3 * C_ * C_ * 2;       // 6 MB
  bf16* wob   = (bf16*)ws; ws += (size_t)C_ * C_ * 2;           // 2 MB
  bf16* qkvb  = (bf16*)ws; ws += (size_t)BT_ * QKV_S * 2;       // 24 MB
  bf16* vtb   = (bf16*)ws; ws += (size_t)B_ * H_ * D_ * T_ * 2; // 8 MB
  float* bqkv = (float*)ws; ws += (size_t)3 * C_ * 4;           // 12 KB
  bf16* yb    = xb;  // x dead after QKV GEMM

  hipMemcpyAsync(bqkv,          bq, C_ * 4, hipMemcpyDeviceToDevice, stream);
  hipMemcpyAsync(bqkv + C_,     bk, C_ * 4, hipMemcpyDeviceToDevice, stream);
  hipMemcpyAsync(bqkv + 2 * C_, bv, C_ * 4, hipMemcpyDeviceToDevice, stream);

  auto cast = [&](const float* src, bf16* dst, int n) {
    int thr = n / 4;
    int blocks = (thr + 255) / 256;
    if (blocks > 4096) blocks = 4096;
    cast_f32_bf16<<<dim3(blocks), dim3(256), 0, stream>>>(src, dst, n);
  };
  cast(x,  xb,  BT_ * C_);
  cast(Wq, wqkvb,               C_ * C_);
  cast(Wk, wqkvb + C_ * C_,     C_ * C_);
  cast(Wv, wqkvb + 2 * C_ * C_, C_ * C_);
  cast(Wo, wob, C_ * C_);

  // fused QKV projection: [BT,1024] @ [3072,1024]^T -> [BT,3072]
  gemm_bt<bf16><<<dim3(QKV_S / 128, BT_ / 128), dim3(256), 0, stream>>>(xb, wqkvb, bqkv, qkvb, BT_, QKV_S, C_);

  transpose_v<<<dim3(T_ / 64, B_ * H_), dim3(256), 0, stream>>>(qkvb, vtb);

  attn_kernel<<<dim3(T_ / 64, B_ * H_), dim3(256), 0, stream>>>(qkvb, vtb, yb);

  gemm_bt<float><<<dim3(C_ / 128, BT_ / 128), dim3(256), 0, stream>>>(yb, wob, bo, out, BT_, C_, C_);
}

// Round 4
// 260.167 us; speedup vs baseline: 1.6764x; 1.6764x over previous
//
#include <hip/hip_runtime.h>
#include <hip/hip_bf16.h>
#include <cstdint>
#include <cstddef>

#define B_ 2
#define T_ 2048
#define C_ 1024
#define H_ 16
#define D_ 64
#define BT_ (B_*T_)
#define QKV_S 3072

typedef __bf16 bf16;
typedef __bf16 bf16x4 __attribute__((ext_vector_type(4)));
typedef __bf16 bf16x8 __attribute__((ext_vector_type(8)));
typedef float f32x4 __attribute__((ext_vector_type(4)));

// ---------------------------------------------------------------- cast f32->bf16
__global__ __launch_bounds__(256) void cast_f32_bf16(const float* __restrict__ in,
                                                     bf16* __restrict__ out, int n) {
  int stride = gridDim.x * blockDim.x;
  for (int i = blockIdx.x * blockDim.x + threadIdx.x; i * 4 < n; i += stride) {
    float4 v = *reinterpret_cast<const float4*>(in + (size_t)i * 4);
    bf16x4 o;
    o[0] = (bf16)v.x; o[1] = (bf16)v.y; o[2] = (bf16)v.z; o[3] = (bf16)v.w;
    *reinterpret_cast<bf16x4*>(out + (size_t)i * 4) = o;
  }
}

// ---------------------------------------------------------------- GEMM: C = A @ B^T + bias
// A [M,K] bf16 row-major, Bm [N,K] bf16 row-major, bias [N] f32.
// 128x128 tile, BK=32, 256 threads = 4 waves (2x2), each wave 64x64 = 4x4 frags.
template<typename OutT>
__global__ __launch_bounds__(256) void gemm_bt(const bf16* __restrict__ A,
                                               const bf16* __restrict__ Bm,
                                               const float* __restrict__ bias,
                                               OutT* __restrict__ Cout,
                                               int M, int N, int K) {
  __shared__ bf16 As[128 * 32];
  __shared__ bf16 Bs[128 * 32];
  const int tid = threadIdx.x;
  const int wid = tid >> 6, lane = tid & 63;
  const int grp = lane >> 4, li = lane & 15;
  const int wr = wid >> 1, wc = wid & 1;
  const int m0 = blockIdx.y * 128, n0 = blockIdx.x * 128;

  f32x4 acc[4][4] = {};

  const int srow = lane >> 2;         // 0..15
  const int scol = (lane & 3) * 8;    // 0,8,16,24

  for (int k0 = 0; k0 < K; k0 += 32) {
#pragma unroll
    for (int p = 0; p < 2; ++p) {
      const int rbase = (p * 4 + wid) * 16;
      const bf16* ga = A + (size_t)(m0 + rbase + srow) * K + (k0 + scol);
      const bf16* gb = Bm + (size_t)(n0 + rbase + srow) * K + (k0 + scol);
      bf16* la = As + (p * 4 + wid) * 512;
      bf16* lb = Bs + (p * 4 + wid) * 512;
      __builtin_amdgcn_global_load_lds((__attribute__((address_space(1))) void*)ga,
                                       (__attribute__((address_space(3))) void*)la, 16, 0, 0);
      __builtin_amdgcn_global_load_lds((__attribute__((address_space(1))) void*)gb,
                                       (__attribute__((address_space(3))) void*)lb, 16, 0, 0);
    }
    __syncthreads();

    bf16x8 af[4], bfr[4];
#pragma unroll
    for (int m = 0; m < 4; ++m)
      af[m] = *reinterpret_cast<const bf16x8*>(&As[(wr * 64 + m * 16 + li) * 32 + grp * 8]);
#pragma unroll
    for (int n = 0; n < 4; ++n)
      bfr[n] = *reinterpret_cast<const bf16x8*>(&Bs[(wc * 64 + n * 16 + li) * 32 + grp * 8]);
#pragma unroll
    for (int m = 0; m < 4; ++m)
#pragma unroll
      for (int n = 0; n < 4; ++n)
        acc[m][n] = __builtin_amdgcn_mfma_f32_16x16x32_bf16(af[m], bfr[n], acc[m][n], 0, 0, 0);
    __syncthreads();
  }

  float bcol[4];
#pragma unroll
  for (int n = 0; n < 4; ++n) bcol[n] = bias[n0 + wc * 64 + n * 16 + li];
#pragma unroll
  for (int m = 0; m < 4; ++m) {
#pragma unroll
    for (int n = 0; n < 4; ++n) {
      const int col = n0 + wc * 64 + n * 16 + li;
#pragma unroll
      for (int j = 0; j < 4; ++j) {
        const int row = m0 + wr * 64 + m * 16 + grp * 4 + j;
        float v = acc[m][n][j] + bcol[n];
        Cout[(size_t)row * N + col] = (OutT)v;
      }
    }
  }
}

// ---------------------------------------------------------------- V transpose: qkv v-part -> Vt[bh][d][T]
__global__ __launch_bounds__(256) void transpose_v(const bf16* __restrict__ qkv,
                                                   bf16* __restrict__ Vt) {
  __shared__ bf16 tile[64 * 72];
  const int tid = threadIdx.x;
  const int t0 = blockIdx.x * 64, bh = blockIdx.y;
  const int b = bh >> 4, h = bh & 15;
#pragma unroll
  for (int p = 0; p < 2; ++p) {
    int idx = p * 256 + tid;
    int r = idx >> 3, c = (idx & 7) * 8;
    bf16x8 v = *reinterpret_cast<const bf16x8*>(qkv + (size_t)(b * T_ + t0 + r) * QKV_S + 2 * C_ + h * D_ + c);
    *reinterpret_cast<bf16x8*>(&tile[r * 72 + c]) = v;
  }
  __syncthreads();
#pragma unroll
  for (int p = 0; p < 2; ++p) {
    int idx = p * 256 + tid;
    int d = idx >> 3, tc = (idx & 7) * 8;
    bf16x8 o;
#pragma unroll
    for (int j = 0; j < 8; ++j) o[j] = tile[(tc + j) * 72 + d];
    *reinterpret_cast<bf16x8*>(Vt + ((size_t)bh * D_ + d) * T_ + t0 + tc) = o;
  }
}

// ---------------------------------------------------------------- flash attention w/ ALiBi
// Swapped-operand (S^T = K@Q^T) flash attention, double-buffered LDS staging,
// one __syncthreads per kv tile (STAGE(t+1); compute(t); sync  — T3 minimal 2-phase).
// qkv: [B*T,3072] bf16 (q at h*64, k at 1024+h*64). Vt: [B*H,64,T] bf16. Y: [B*T,1024] bf16.
// Grid (T/64, B*H), block 256 = 4 waves; wave w owns q rows q0+w*16..+15 (lane li = its q row).
// K/V LDS: linear [64 rows][128 B], content XOR-swizzled via pre-swizzled GLOBAL source
// (byte ^= (row&7)<<4); every read applies the same XOR (rule: both-sides-or-neither).
__global__ __launch_bounds__(256) void attn_kernel(const bf16* __restrict__ qkv,
                                                   const bf16* __restrict__ Vt,
                                                   bf16* __restrict__ Y) {
  __shared__ bf16 Ks[2][64 * 64];
  __shared__ bf16 Vs[2][64 * 64];
  __shared__ bf16 Ps[4 * 16 * 72];   // per-wave [16 q][72] padded relayout buffer

  const int tid = threadIdx.x;
  const int wid = tid >> 6, lane = tid & 63;
  const int grp = lane >> 4, li = lane & 15;
  const int qt = gridDim.x - 1 - blockIdx.x;   // heavy blocks first
  const int bh = blockIdx.y;
  const int b = bh >> 4, h = bh & 15;
  const int q0 = qt * 64;
  const int qi = q0 + wid * 16 + li;           // this lane's q row
  const float slope = exp2f(-0.5f * (float)(h + 1));

  bf16* Pw = Ps + wid * (16 * 72);

  // Q fragments (B-operand: row=li<->q, k=d), pre-scaled by 1/8 (exact in bf16)
  bf16x8 qf[2];
  {
    const bf16* qrow = qkv + (size_t)(b * T_ + qi) * QKV_S + h * D_;
    qf[0] = *reinterpret_cast<const bf16x8*>(qrow + grp * 8);
    qf[1] = *reinterpret_cast<const bf16x8*>(qrow + 32 + grp * 8);
#pragma unroll
    for (int c = 0; c < 2; ++c)
#pragma unroll
      for (int j = 0; j < 8; ++j)
        qf[c][j] = (bf16)((float)qf[c][j] * 0.125f);
  }

  f32x4 oacc[4] = {};      // O^T: [d = nd*16+grp*4+j][q = li]
  float mrun = -1e30f, lrun = 0.f;

  const bf16* Kbase = qkv + (size_t)b * T_ * QKV_S + C_ + (size_t)h * D_;
  const bf16* Vbase = Vt + (size_t)bh * D_ * T_;

  const int srow = lane >> 3;                         // dest row & 7
  const int sswz = ((lane & 7) * 16) ^ (srow << 4);   // inverse-swizzled source byte col
  const int rsw = (li & 7) << 4;                      // read byte XOR (row&7)<<4, row%8==li%8

  // stage kv tile kv0 into buffer bufi (4 x global_load_lds 16B per thread)
  auto stage = [&](int kv0, int bufi) __attribute__((always_inline)) {
#pragma unroll
    for (int p = 0; p < 2; ++p) {
      const int rbase = p * 32 + wid * 8;
      const int row = rbase + srow;
      const bf16* gk = Kbase + (size_t)(kv0 + row) * QKV_S + (sswz >> 1);
      const bf16* gv = Vbase + (size_t)row * T_ + kv0 + (sswz >> 1);
      __builtin_amdgcn_global_load_lds((__attribute__((address_space(1))) void*)gk,
                                       (__attribute__((address_space(3))) void*)(&Ks[bufi][rbase * 64]), 16, 0, 0);
      __builtin_amdgcn_global_load_lds((__attribute__((address_space(1))) void*)gv,
                                       (__attribute__((address_space(3))) void*)(&Vs[bufi][rbase * 64]), 16, 0, 0);
    }
  };

  auto compute = [&](int kv0, int bufi, bool masked) __attribute__((always_inline)) {
    const char* Kb = (const char*)&Ks[bufi][0];
    const char* Vb = (const char*)&Vs[bufi][0];

    // S^T = K @ Q^T : K frags are A-operand rows (kv = n*16+li), k = d
    f32x4 s[4] = {};
#pragma unroll
    for (int n = 0; n < 4; ++n) {
      const char* kr = Kb + (n * 16 + li) * 128;
      bf16x8 kf0 = *reinterpret_cast<const bf16x8*>(kr + ((grp * 16) ^ rsw));
      bf16x8 kf1 = *reinterpret_cast<const bf16x8*>(kr + ((64 + grp * 16) ^ rsw));
      s[n] = __builtin_amdgcn_mfma_f32_16x16x32_bf16(kf0, qf[0], s[n], 0, 0, 0);
      s[n] = __builtin_amdgcn_mfma_f32_16x16x32_bf16(kf1, qf[1], s[n], 0, 0, 0);
    }

    // lane-local softmax over 16 kv regs (kv = kv0 + n*16 + grp*4 + j); 2 shuffles per reduce
    float p[4][4];
    float rm = -1e30f;
#pragma unroll
    for (int n = 0; n < 4; ++n)
#pragma unroll
      for (int j = 0; j < 4; ++j) {
        const int kv = kv0 + n * 16 + grp * 4 + j;
        float sv = fmaf(-slope, (float)(qi - kv), s[n][j]);
        if (masked) sv = (kv <= qi) ? sv : -1e30f;
        p[n][j] = sv;
        rm = fmaxf(rm, sv);
      }
    rm = fmaxf(rm, __shfl_xor(rm, 16, 64));
    rm = fmaxf(rm, __shfl_xor(rm, 32, 64));
    const float mnew = fmaxf(mrun, rm);
    const float alpha = __expf(mrun - mnew);
    mrun = mnew;
    float rs = 0.f;
#pragma unroll
    for (int n = 0; n < 4; ++n)
#pragma unroll
      for (int j = 0; j < 4; ++j) {
        float e = __expf(p[n][j] - mnew);
        p[n][j] = e;
        rs += e;
      }
    rs += __shfl_xor(rs, 16, 64);
    rs += __shfl_xor(rs, 32, 64);
    lrun = lrun * alpha + rs;
#pragma unroll
    for (int nd = 0; nd < 4; ++nd)
#pragma unroll
      for (int j = 0; j < 4; ++j)
        oacc[nd][j] *= alpha;

    // P relayout through per-wave LDS: lane li owns q-row; B-operand needs row=q=li, k=kv
#pragma unroll
    for (int n = 0; n < 4; ++n) {
      bf16x4 p4;
#pragma unroll
      for (int j = 0; j < 4; ++j) p4[j] = (bf16)p[n][j];
      *reinterpret_cast<bf16x4*>(Pw + li * 72 + n * 16 + grp * 4) = p4;
    }
    asm volatile("s_waitcnt lgkmcnt(0)" ::: "memory");
    __builtin_amdgcn_sched_barrier(0);

    // O^T += Vt-tile @ P^T : V frags are A-operand rows (d = nd*16+li), k = kv
#pragma unroll
    for (int kc = 0; kc < 2; ++kc) {
      bf16x8 pb = *reinterpret_cast<const bf16x8*>(Pw + li * 72 + kc * 32 + grp * 8);
#pragma unroll
      for (int nd = 0; nd < 4; ++nd) {
        const char* vrp = Vb + (nd * 16 + li) * 128;
        bf16x8 vf = *reinterpret_cast<const bf16x8*>(vrp + ((kc * 64 + grp * 16) ^ rsw));
        oacc[nd] = __builtin_amdgcn_mfma_f32_16x16x32_bf16(vf, pb, oacc[nd], 0, 0, 0);
      }
    }
  };

  const int nt = qt + 1;
  stage(0, 0);
  __syncthreads();
  int cur = 0;
  for (int t = 0; t < nt; ++t) {
    if (t + 1 < nt) stage((t + 1) * 64, cur ^ 1);
    compute(t * 64, cur, t == nt - 1);
    __syncthreads();   // vmcnt(0)+lgkmcnt(0)+barrier: next tile staged, buffers safe to flip
    cur ^= 1;
  }

  // epilogue: O^T/l -> transpose via Pw -> Y rows (coalesced 16B)
  const float rinv = 1.f / lrun;
#pragma unroll
  for (int nd = 0; nd < 4; ++nd) {
    bf16x4 o4;
#pragma unroll
    for (int j = 0; j < 4; ++j) o4[j] = (bf16)(oacc[nd][j] * rinv);
    *reinterpret_cast<bf16x4*>(Pw + li * 72 + nd * 16 + grp * 4) = o4;
  }
  asm volatile("s_waitcnt lgkmcnt(0)" ::: "memory");
  __builtin_amdgcn_sched_barrier(0);
  {
    bf16* yrow = Y + (size_t)(b * T_ + qi) * C_ + h * D_;
#pragma unroll
    for (int c = 0; c < 2; ++c) {
      bf16x8 y8 = *reinterpret_cast<const bf16x8*>(Pw + li * 72 + (c * 4 + grp) * 8);
      *reinterpret_cast<bf16x8*>(yrow + (c * 4 + grp) * 8) = y8;
    }
  }
}

// ---------------------------------------------------------------- launch
extern "C" void kernel_launch(void* const* d_in, const int* in_sizes, int n_in,
                              void* d_out, int out_size, void* d_ws, size_t ws_size,
                              hipStream_t stream) {
  const float* x  = (const float*)d_in[0];
  const float* Wq = (const float*)d_in[1];
  const float* bq = (const float*)d_in[2];
  const float* Wk = (const float*)d_in[3];
  const float* bk = (const float*)d_in[4];
  const float* Wv = (const float*)d_in[5];
  const float* bv = (const float*)d_in[6];
  const float* Wo = (const float*)d_in[7];
  const float* bo = (const float*)d_in[8];
  float* out = (float*)d_out;

  char* ws = (char*)d_ws;
  bf16* xb    = (bf16*)ws; ws += (size_t)BT_ * C_ * 2;          // 8 MB (reused as yb)
  bf16* wqkvb = (bf16*)ws; ws += (size_t)3 * C_ * C_ * 2;       // 6 MB
  bf16* wob   = (bf16*)ws; ws += (size_t)C_ * C_ * 2;           // 2 MB
  bf16* qkvb  = (bf16*)ws; ws += (size_t)BT_ * QKV_S * 2;       // 24 MB
  bf16* vtb   = (bf16*)ws; ws += (size_t)B_ * H_ * D_ * T_ * 2; // 8 MB
  float* bqkv = (float*)ws; ws += (size_t)3 * C_ * 4;           // 12 KB
  bf16* yb    = xb;  // x dead after QKV GEMM

  hipMemcpyAsync(bqkv,          bq, C_ * 4, hipMemcpyDeviceToDevice, stream);
  hipMemcpyAsync(bqkv + C_,     bk, C_ * 4, hipMemcpyDeviceToDevice, stream);
  hipMemcpyAsync(bqkv + 2 * C_, bv, C_ * 4, hipMemcpyDeviceToDevice, stream);

  auto cast = [&](const float* src, bf16* dst, int n) {
    int thr = n / 4;
    int blocks = (thr + 255) / 256;
    if (blocks > 4096) blocks = 4096;
    cast_f32_bf16<<<dim3(blocks), dim3(256), 0, stream>>>(src, dst, n);
  };
  cast(x,  xb,  BT_ * C_);
  cast(Wq, wqkvb,               C_ * C_);
  cast(Wk, wqkvb + C_ * C_,     C_ * C_);
  cast(Wv, wqkvb + 2 * C_ * C_, C_ * C_);
  cast(Wo, wob, C_ * C_);

  // fused QKV projection: [BT,1024] @ [3072,1024]^T -> [BT,3072]
  gemm_bt<bf16><<<dim3(QKV_S / 128, BT_ / 128), dim3(256), 0, stream>>>(xb, wqkvb, bqkv, qkvb, BT_, QKV_S, C_);

  transpose_v<<<dim3(T_ / 64, B_ * H_), dim3(256), 0, stream>>>(qkvb, vtb);

  attn_kernel<<<dim3(T_ / 64, B_ * H_), dim3(256), 0, stream>>>(qkvb, vtb, yb);

  gemm_bt<float><<<dim3(C_ / 128, BT_ / 128), dim3(256), 0, stream>>>(yb, wob, bo, out, BT_, C_, C_);
}

// Round 5
// 243.188 us; speedup vs baseline: 1.7934x; 1.0698x over previous
//
#include <hip/hip_runtime.h>
#include <hip/hip_bf16.h>
#include <cstdint>
#include <cstddef>

#define B_ 2
#define T_ 2048
#define C_ 1024
#define H_ 16
#define D_ 64
#define BT_ (B_*T_)
#define QKV_S 3072

typedef __bf16 bf16;
typedef __bf16 bf16x4 __attribute__((ext_vector_type(4)));
typedef __bf16 bf16x8 __attribute__((ext_vector_type(8)));
typedef float f32x4 __attribute__((ext_vector_type(4)));

// ---------------------------------------------------------------- cast f32->bf16
__global__ __launch_bounds__(256) void cast_f32_bf16(const float* __restrict__ in,
                                                     bf16* __restrict__ out, int n) {
  int stride = gridDim.x * blockDim.x;
  for (int i = blockIdx.x * blockDim.x + threadIdx.x; i * 4 < n; i += stride) {
    float4 v = *reinterpret_cast<const float4*>(in + (size_t)i * 4);
    bf16x4 o;
    o[0] = (bf16)v.x; o[1] = (bf16)v.y; o[2] = (bf16)v.z; o[3] = (bf16)v.w;
    *reinterpret_cast<bf16x4*>(out + (size_t)i * 4) = o;
  }
}

// ---------------------------------------------------------------- GEMM: C = A @ B^T + bias
// A [M,K] bf16 row-major, Bm [N,K] bf16 row-major, bias [N] f32.
// 128x128 tile, BK=32, 256 threads = 4 waves (2x2), each wave 64x64 = 4x4 frags.
template<typename OutT>
__global__ __launch_bounds__(256) void gemm_bt(const bf16* __restrict__ A,
                                               const bf16* __restrict__ Bm,
                                               const float* __restrict__ bias,
                                               OutT* __restrict__ Cout,
                                               int M, int N, int K) {
  __shared__ bf16 As[128 * 32];
  __shared__ bf16 Bs[128 * 32];
  const int tid = threadIdx.x;
  const int wid = tid >> 6, lane = tid & 63;
  const int grp = lane >> 4, li = lane & 15;
  const int wr = wid >> 1, wc = wid & 1;
  const int m0 = blockIdx.y * 128, n0 = blockIdx.x * 128;

  f32x4 acc[4][4] = {};

  const int srow = lane >> 2;         // 0..15
  const int scol = (lane & 3) * 8;    // 0,8,16,24

  for (int k0 = 0; k0 < K; k0 += 32) {
#pragma unroll
    for (int p = 0; p < 2; ++p) {
      const int rbase = (p * 4 + wid) * 16;
      const bf16* ga = A + (size_t)(m0 + rbase + srow) * K + (k0 + scol);
      const bf16* gb = Bm + (size_t)(n0 + rbase + srow) * K + (k0 + scol);
      bf16* la = As + (p * 4 + wid) * 512;
      bf16* lb = Bs + (p * 4 + wid) * 512;
      __builtin_amdgcn_global_load_lds((__attribute__((address_space(1))) void*)ga,
                                       (__attribute__((address_space(3))) void*)la, 16, 0, 0);
      __builtin_amdgcn_global_load_lds((__attribute__((address_space(1))) void*)gb,
                                       (__attribute__((address_space(3))) void*)lb, 16, 0, 0);
    }
    __syncthreads();

    bf16x8 af[4], bfr[4];
#pragma unroll
    for (int m = 0; m < 4; ++m)
      af[m] = *reinterpret_cast<const bf16x8*>(&As[(wr * 64 + m * 16 + li) * 32 + grp * 8]);
#pragma unroll
    for (int n = 0; n < 4; ++n)
      bfr[n] = *reinterpret_cast<const bf16x8*>(&Bs[(wc * 64 + n * 16 + li) * 32 + grp * 8]);
#pragma unroll
    for (int m = 0; m < 4; ++m)
#pragma unroll
      for (int n = 0; n < 4; ++n)
        acc[m][n] = __builtin_amdgcn_mfma_f32_16x16x32_bf16(af[m], bfr[n], acc[m][n], 0, 0, 0);
    __syncthreads();
  }

  float bcol[4];
#pragma unroll
  for (int n = 0; n < 4; ++n) bcol[n] = bias[n0 + wc * 64 + n * 16 + li];
#pragma unroll
  for (int m = 0; m < 4; ++m) {
#pragma unroll
    for (int n = 0; n < 4; ++n) {
      const int col = n0 + wc * 64 + n * 16 + li;
#pragma unroll
      for (int j = 0; j < 4; ++j) {
        const int row = m0 + wr * 64 + m * 16 + grp * 4 + j;
        float v = acc[m][n][j] + bcol[n];
        Cout[(size_t)row * N + col] = (OutT)v;
      }
    }
  }
}

// ---------------------------------------------------------------- V transpose: qkv v-part -> Vt[bh][d][T]
__global__ __launch_bounds__(256) void transpose_v(const bf16* __restrict__ qkv,
                                                   bf16* __restrict__ Vt) {
  __shared__ bf16 tile[64 * 72];
  const int tid = threadIdx.x;
  const int t0 = blockIdx.x * 64, bh = blockIdx.y;
  const int b = bh >> 4, h = bh & 15;
#pragma unroll
  for (int p = 0; p < 2; ++p) {
    int idx = p * 256 + tid;
    int r = idx >> 3, c = (idx & 7) * 8;
    bf16x8 v = *reinterpret_cast<const bf16x8*>(qkv + (size_t)(b * T_ + t0 + r) * QKV_S + 2 * C_ + h * D_ + c);
    *reinterpret_cast<bf16x8*>(&tile[r * 72 + c]) = v;
  }
  __syncthreads();
#pragma unroll
  for (int p = 0; p < 2; ++p) {
    int idx = p * 256 + tid;
    int d = idx >> 3, tc = (idx & 7) * 8;
    bf16x8 o;
#pragma unroll
    for (int j = 0; j < 8; ++j) o[j] = tile[(tc + j) * 72 + d];
    *reinterpret_cast<bf16x8*>(Vt + ((size_t)bh * D_ + d) * T_ + t0 + tc) = o;
  }
}

// ---------------------------------------------------------------- flash attention w/ ALiBi
// Swapped-operand (S^T = K@Q^T) flash attention; 8 waves x 16 q-rows = QBLK 128;
// double-buffered K/V LDS; one __syncthreads per kv tile (STAGE(t+1); compute(t); sync).
// qkv: [B*T,3072] bf16 (q at h*64, k at 1024+h*64). Vt: [B*H,64,T] bf16. Y: [B*T,1024] bf16.
// Grid (T/128, B*H), block 512. Wave w owns q rows q0+w*16..+15 (lane li = its q row).
// K/V LDS: linear [64 rows][128 B], content XOR-swizzled via pre-swizzled GLOBAL source
// (byte ^= (row&7)<<4); every read applies the same XOR (rule: both-sides-or-neither).
__global__ __launch_bounds__(512) void attn_kernel(const bf16* __restrict__ qkv,
                                                   const bf16* __restrict__ Vt,
                                                   bf16* __restrict__ Y) {
  __shared__ bf16 Ks[2][64 * 64];
  __shared__ bf16 Vs[2][64 * 64];
  __shared__ bf16 Ps[8 * 16 * 72];   // per-wave [16 q][72] padded relayout buffer

  const int tid = threadIdx.x;
  const int wid = tid >> 6, lane = tid & 63;
  const int grp = lane >> 4, li = lane & 15;
  const int QT = gridDim.x - 1 - blockIdx.x;   // heavy blocks first
  const int bh = blockIdx.y;
  const int b = bh >> 4, h = bh & 15;
  const int q0 = QT * 128;
  const int wq0 = q0 + wid * 16;               // wave's first q row
  const int qi = wq0 + li;                     // this lane's q row
  const float slope = exp2f(-0.5f * (float)(h + 1));

  bf16* Pw = Ps + wid * (16 * 72);

  // Q fragments (B-operand: row=li<->q, k=d), pre-scaled by 1/8 (exact in bf16)
  bf16x8 qf[2];
  {
    const bf16* qrow = qkv + (size_t)(b * T_ + qi) * QKV_S + h * D_;
    qf[0] = *reinterpret_cast<const bf16x8*>(qrow + grp * 8);
    qf[1] = *reinterpret_cast<const bf16x8*>(qrow + 32 + grp * 8);
#pragma unroll
    for (int c = 0; c < 2; ++c)
#pragma unroll
      for (int j = 0; j < 8; ++j)
        qf[c][j] = (bf16)((float)qf[c][j] * 0.125f);
  }

  f32x4 oacc[4] = {};      // O^T: [d = nd*16+grp*4+j][q = li]
  float mrun = -1e30f, lrun = 0.f;

  const bf16* Kbase = qkv + (size_t)b * T_ * QKV_S + C_ + (size_t)h * D_;
  const bf16* Vbase = Vt + (size_t)bh * D_ * T_;

  // staging geometry: 512 threads x 16B = one 64x128B tile; thread t -> row t>>3, bytecol (t&7)*16
  const int strow = tid >> 3;
  const int stswz = ((tid & 7) * 16) ^ ((strow & 7) << 4);  // inverse-swizzled source byte col
  const int rsw = (li & 7) << 4;                            // read byte XOR ((row&7)<<4)

  auto stage = [&](int kv0, int bufi) __attribute__((always_inline)) {
    const bf16* gk = Kbase + (size_t)(kv0 + strow) * QKV_S + (stswz >> 1);
    const bf16* gv = Vbase + (size_t)strow * T_ + kv0 + (stswz >> 1);
    __builtin_amdgcn_global_load_lds((__attribute__((address_space(1))) void*)gk,
                                     (__attribute__((address_space(3))) void*)(&Ks[bufi][wid * 512]), 16, 0, 0);
    __builtin_amdgcn_global_load_lds((__attribute__((address_space(1))) void*)gv,
                                     (__attribute__((address_space(3))) void*)(&Vs[bufi][wid * 512]), 16, 0, 0);
  };

  auto compute = [&](int kv0, int bufi, bool masked) __attribute__((always_inline)) {
    const char* Kb = (const char*)&Ks[bufi][0];
    const char* Vb = (const char*)&Vs[bufi][0];

    // S^T = K @ Q^T : K frags are A-operand rows (kv = n*16+li), k = d
    f32x4 s[4] = {};
    __builtin_amdgcn_s_setprio(1);
#pragma unroll
    for (int n = 0; n < 4; ++n) {
      const char* kr = Kb + (n * 16 + li) * 128;
      bf16x8 kf0 = *reinterpret_cast<const bf16x8*>(kr + ((grp * 16) ^ rsw));
      bf16x8 kf1 = *reinterpret_cast<const bf16x8*>(kr + ((64 + grp * 16) ^ rsw));
      s[n] = __builtin_amdgcn_mfma_f32_16x16x32_bf16(kf0, qf[0], s[n], 0, 0, 0);
      s[n] = __builtin_amdgcn_mfma_f32_16x16x32_bf16(kf1, qf[1], s[n], 0, 0, 0);
    }
    __builtin_amdgcn_s_setprio(0);

    // lane-local softmax over 16 kv regs (kv = kv0 + n*16 + grp*4 + j); 2 shuffles per reduce
    float p[4][4];
    float rm = -1e30f;
#pragma unroll
    for (int n = 0; n < 4; ++n)
#pragma unroll
      for (int j = 0; j < 4; ++j) {
        const int kv = kv0 + n * 16 + grp * 4 + j;
        float sv = fmaf(-slope, (float)(qi - kv), s[n][j]);
        if (masked) sv = (kv <= qi) ? sv : -1e30f;
        p[n][j] = sv;
        rm = fmaxf(rm, sv);
      }
    rm = fmaxf(rm, __shfl_xor(rm, 16, 64));
    rm = fmaxf(rm, __shfl_xor(rm, 32, 64));
    const float mnew = fmaxf(mrun, rm);
    const float alpha = __expf(mrun - mnew);
    mrun = mnew;
    float rs = 0.f;
#pragma unroll
    for (int n = 0; n < 4; ++n)
#pragma unroll
      for (int j = 0; j < 4; ++j) {
        float e = __expf(p[n][j] - mnew);
        p[n][j] = e;
        rs += e;
      }
    rs += __shfl_xor(rs, 16, 64);
    rs += __shfl_xor(rs, 32, 64);
    lrun = lrun * alpha + rs;
#pragma unroll
    for (int nd = 0; nd < 4; ++nd)
#pragma unroll
      for (int j = 0; j < 4; ++j)
        oacc[nd][j] *= alpha;

    // P relayout through per-wave LDS: lane li owns q-row; B-operand needs row=q=li, k=kv
#pragma unroll
    for (int n = 0; n < 4; ++n) {
      bf16x4 p4;
#pragma unroll
      for (int j = 0; j < 4; ++j) p4[j] = (bf16)p[n][j];
      *reinterpret_cast<bf16x4*>(Pw + li * 72 + n * 16 + grp * 4) = p4;
    }
    asm volatile("s_waitcnt lgkmcnt(0)" ::: "memory");
    __builtin_amdgcn_sched_barrier(0);

    // O^T += Vt-tile @ P^T : V frags are A-operand rows (d = nd*16+li), k = kv
    __builtin_amdgcn_s_setprio(1);
#pragma unroll
    for (int kc = 0; kc < 2; ++kc) {
      bf16x8 pb = *reinterpret_cast<const bf16x8*>(Pw + li * 72 + kc * 32 + grp * 8);
#pragma unroll
      for (int nd = 0; nd < 4; ++nd) {
        const char* vrp = Vb + (nd * 16 + li) * 128;
        bf16x8 vf = *reinterpret_cast<const bf16x8*>(vrp + ((kc * 64 + grp * 16) ^ rsw));
        oacc[nd] = __builtin_amdgcn_mfma_f32_16x16x32_bf16(vf, pb, oacc[nd], 0, 0, 0);
      }
    }
    __builtin_amdgcn_s_setprio(0);
  };

  const int nt = 2 * QT + 2;
  stage(0, 0);
  __syncthreads();
  int cur = 0;
  for (int t = 0; t < nt; ++t) {
    const int kv0 = t * 64;
    if (t + 1 < nt) stage((t + 1) * 64, cur ^ 1);
    if (kv0 <= wq0) compute(kv0, cur, kv0 + 64 > wq0);   // wave-uniform skip past diagonal
    __syncthreads();   // vmcnt+lgkm drain + barrier: next tile staged, buffers safe to flip
    cur ^= 1;
  }

  // epilogue: O^T/l -> transpose via Pw -> Y rows (coalesced 16B)
  const float rinv = 1.f / lrun;
#pragma unroll
  for (int nd = 0; nd < 4; ++nd) {
    bf16x4 o4;
#pragma unroll
    for (int j = 0; j < 4; ++j) o4[j] = (bf16)(oacc[nd][j] * rinv);
    *reinterpret_cast<bf16x4*>(Pw + li * 72 + nd * 16 + grp * 4) = o4;
  }
  asm volatile("s_waitcnt lgkmcnt(0)" ::: "memory");
  __builtin_amdgcn_sched_barrier(0);
  {
    bf16* yrow = Y + (size_t)(b * T_ + qi) * C_ + h * D_;
#pragma unroll
    for (int c = 0; c < 2; ++c) {
      bf16x8 y8 = *reinterpret_cast<const bf16x8*>(Pw + li * 72 + (c * 4 + grp) * 8);
      *reinterpret_cast<bf16x8*>(yrow + (c * 4 + grp) * 8) = y8;
    }
  }
}

// ---------------------------------------------------------------- launch
extern "C" void kernel_launch(void* const* d_in, const int* in_sizes, int n_in,
                              void* d_out, int out_size, void* d_ws, size_t ws_size,
                              hipStream_t stream) {
  const float* x  = (const float*)d_in[0];
  const float* Wq = (const float*)d_in[1];
  const float* bq = (const float*)d_in[2];
  const float* Wk = (const float*)d_in[3];
  const float* bk = (const float*)d_in[4];
  const float* Wv = (const float*)d_in[5];
  const float* bv = (const float*)d_in[6];
  const float* Wo = (const float*)d_in[7];
  const float* bo = (const float*)d_in[8];
  float* out = (float*)d_out;

  char* ws = (char*)d_ws;
  bf16* xb    = (bf16*)ws; ws += (size_t)BT_ * C_ * 2;          // 8 MB (reused as yb)
  bf16* wqkvb = (bf16*)ws; ws += (size_t)3 * C_ * C_ * 2;       // 6 MB
  bf16* wob   = (bf16*)ws; ws += (size_t)C_ * C_ * 2;           // 2 MB
  bf16* qkvb  = (bf16*)ws; ws += (size_t)BT_ * QKV_S * 2;       // 24 MB
  bf16* vtb   = (bf16*)ws; ws += (size_t)B_ * H_ * D_ * T_ * 2; // 8 MB
  float* bqkv = (float*)ws; ws += (size_t)3 * C_ * 4;           // 12 KB
  bf16* yb    = xb;  // x dead after QKV GEMM

  hipMemcpyAsync(bqkv,          bq, C_ * 4, hipMemcpyDeviceToDevice, stream);
  hipMemcpyAsync(bqkv + C_,     bk, C_ * 4, hipMemcpyDeviceToDevice, stream);
  hipMemcpyAsync(bqkv + 2 * C_, bv, C_ * 4, hipMemcpyDeviceToDevice, stream);

  auto cast = [&](const float* src, bf16* dst, int n) {
    int thr = n / 4;
    int blocks = (thr + 255) / 256;
    if (blocks > 4096) blocks = 4096;
    cast_f32_bf16<<<dim3(blocks), dim3(256), 0, stream>>>(src, dst, n);
  };
  cast(x,  xb,  BT_ * C_);
  cast(Wq, wqkvb,               C_ * C_);
  cast(Wk, wqkvb + C_ * C_,     C_ * C_);
  cast(Wv, wqkvb + 2 * C_ * C_, C_ * C_);
  cast(Wo, wob, C_ * C_);

  // fused QKV projection: [BT,1024] @ [3072,1024]^T -> [BT,3072]
  gemm_bt<bf16><<<dim3(QKV_S / 128, BT_ / 128), dim3(256), 0, stream>>>(xb, wqkvb, bqkv, qkvb, BT_, QKV_S, C_);

  transpose_v<<<dim3(T_ / 64, B_ * H_), dim3(256), 0, stream>>>(qkvb, vtb);

  attn_kernel<<<dim3(T_ / 128, B_ * H_), dim3(512), 0, stream>>>(qkvb, vtb, yb);

  gemm_bt<float><<<dim3(C_ / 128, BT_ / 128), dim3(256), 0, stream>>>(yb, wob, bo, out, BT_, C_, C_);
}

// Round 6
// 238.636 us; speedup vs baseline: 1.8276x; 1.0191x over previous
//
#include <hip/hip_runtime.h>
#include <hip/hip_bf16.h>
#include <cstdint>
#include <cstddef>

#define B_ 2
#define T_ 2048
#define C_ 1024
#define H_ 16
#define D_ 64
#define BT_ (B_*T_)
#define QKV_S 3072
#define LOG2E 1.4426950408889634f

typedef __bf16 bf16;
typedef __bf16 bf16x4 __attribute__((ext_vector_type(4)));
typedef __bf16 bf16x8 __attribute__((ext_vector_type(8)));
typedef float f32x4 __attribute__((ext_vector_type(4)));

// ---------------------------------------------------------------- fused cast f32->bf16 (x + 4 weights)
__global__ __launch_bounds__(256) void cast_all(const float* __restrict__ x,
                                                const float* __restrict__ wq,
                                                const float* __restrict__ wk,
                                                const float* __restrict__ wv,
                                                const float* __restrict__ wo,
                                                bf16* __restrict__ xb,
                                                bf16* __restrict__ wqkvb,
                                                bf16* __restrict__ wob) {
  const int X4 = (BT_ * C_) / 4;     // 1048576
  const int W4 = (C_ * C_) / 4;      // 262144
  int i = blockIdx.x * blockDim.x + threadIdx.x;
  if (i >= X4 + 4 * W4) return;
  const float* src;
  bf16* dst;
  int off;
  if (i < X4) {
    src = x; dst = xb; off = i;
  } else {
    int k = i - X4;
    int w = k >> 18;        // /W4
    off = k & (W4 - 1);
    src = (w == 0) ? wq : (w == 1) ? wk : (w == 2) ? wv : wo;
    dst = (w < 3) ? (wqkvb + (size_t)w * C_ * C_) : wob;
  }
  float4 v = reinterpret_cast<const float4*>(src)[off];
  bf16x4 o;
  o[0] = (bf16)v.x; o[1] = (bf16)v.y; o[2] = (bf16)v.z; o[3] = (bf16)v.w;
  *reinterpret_cast<bf16x4*>(dst + (size_t)off * 4) = o;
}

// ---------------------------------------------------------------- GEMM: C = A @ B^T + bias
// A [M,K] bf16 row-major, Bm [N,K] bf16 row-major, bias [N] f32.
// 128x128 tile, BK=32, 256 threads = 4 waves (2x2), each wave 64x64 = 4x4 frags.
// Double-buffered LDS staging: stage(t+1); compute(t); sync  (one barrier per K-step).
// FUSE_VT: blocks with n0 >= 2048 (the V part of the QKV projection) write their
// output transposed to VtOut[bh][d][t] instead of Cout.
template<typename OutT, bool FUSE_VT>
__global__ __launch_bounds__(256) void gemm_bt(const bf16* __restrict__ A,
                                               const bf16* __restrict__ Bm,
                                               const float* __restrict__ bias,
                                               OutT* __restrict__ Cout,
                                               bf16* __restrict__ VtOut,
                                               int M, int N, int K) {
  __shared__ bf16 As[2][128 * 32];
  __shared__ bf16 Bs[2][128 * 32];
  const int tid = threadIdx.x;
  const int wid = tid >> 6, lane = tid & 63;
  const int grp = lane >> 4, li = lane & 15;
  const int wr = wid >> 1, wc = wid & 1;
  const int m0 = blockIdx.y * 128, n0 = blockIdx.x * 128;

  f32x4 acc[4][4] = {};

  const int srow = lane >> 2;         // 0..15
  const int scol = (lane & 3) * 8;    // 0,8,16,24

  auto stage = [&](int k0, int bufi) __attribute__((always_inline)) {
#pragma unroll
    for (int p = 0; p < 2; ++p) {
      const int rbase = (p * 4 + wid) * 16;
      const bf16* ga = A + (size_t)(m0 + rbase + srow) * K + (k0 + scol);
      const bf16* gb = Bm + (size_t)(n0 + rbase + srow) * K + (k0 + scol);
      __builtin_amdgcn_global_load_lds((__attribute__((address_space(1))) void*)ga,
                                       (__attribute__((address_space(3))) void*)(&As[bufi][(p * 4 + wid) * 512]), 16, 0, 0);
      __builtin_amdgcn_global_load_lds((__attribute__((address_space(1))) void*)gb,
                                       (__attribute__((address_space(3))) void*)(&Bs[bufi][(p * 4 + wid) * 512]), 16, 0, 0);
    }
  };

  const int nt = K >> 5;
  stage(0, 0);
  __syncthreads();
  int cur = 0;
  for (int t = 0; t < nt; ++t) {
    if (t + 1 < nt) stage((t + 1) * 32, cur ^ 1);

    bf16x8 af[4], bfr[4];
#pragma unroll
    for (int m = 0; m < 4; ++m)
      af[m] = *reinterpret_cast<const bf16x8*>(&As[cur][(wr * 64 + m * 16 + li) * 32 + grp * 8]);
#pragma unroll
    for (int n = 0; n < 4; ++n)
      bfr[n] = *reinterpret_cast<const bf16x8*>(&Bs[cur][(wc * 64 + n * 16 + li) * 32 + grp * 8]);
#pragma unroll
    for (int m = 0; m < 4; ++m)
#pragma unroll
      for (int n = 0; n < 4; ++n)
        acc[m][n] = __builtin_amdgcn_mfma_f32_16x16x32_bf16(af[m], bfr[n], acc[m][n], 0, 0, 0);

    __syncthreads();   // drains vmcnt (next tile staged) + all waves done with buf cur
    cur ^= 1;
  }

  float bcol[4];
#pragma unroll
  for (int n = 0; n < 4; ++n) bcol[n] = bias[n0 + wc * 64 + n * 16 + li];

  if (FUSE_VT && n0 >= 2 * C_) {
    // V block: write transposed to Vt[b*16+h][d][t]  (col-2048 = h*64+d; row = b*2048+t)
#pragma unroll
    for (int m = 0; m < 4; ++m) {
      const int row0 = m0 + wr * 64 + m * 16 + grp * 4;   // 4-aligned
      const int b = row0 >> 11, t = row0 & (T_ - 1);
#pragma unroll
      for (int n = 0; n < 4; ++n) {
        const int hd = (n0 - 2 * C_) + wc * 64 + n * 16 + li;
        bf16x4 o4;
#pragma unroll
        for (int j = 0; j < 4; ++j) o4[j] = (bf16)(acc[m][n][j] + bcol[n]);
        *reinterpret_cast<bf16x4*>(VtOut + ((size_t)(b * C_ + hd)) * T_ + t) = o4;
      }
    }
  } else {
#pragma unroll
    for (int m = 0; m < 4; ++m) {
#pragma unroll
      for (int n = 0; n < 4; ++n) {
        const int col = n0 + wc * 64 + n * 16 + li;
#pragma unroll
        for (int j = 0; j < 4; ++j) {
          const int row = m0 + wr * 64 + m * 16 + grp * 4 + j;
          float v = acc[m][n][j] + bcol[n];
          Cout[(size_t)row * N + col] = (OutT)v;
        }
      }
    }
  }
}

// ---------------------------------------------------------------- flash attention w/ ALiBi
// Swapped-operand (S^T = K@Q^T) flash attention; 8 waves x 16 q-rows = QBLK 128;
// double-buffered K/V LDS; one __syncthreads per kv tile (STAGE(t+1); compute(t); sync).
// Softmax fully in log2 domain: S2 = S*log2e via fma, p = exp2(S2 - m2).
// qkv: [B*T,3072] bf16 (q at h*64, k at 1024+h*64). Vt: [B*H,64,T] bf16. Y: [B*T,1024] bf16.
// Grid (T/128, B*H), block 512. Wave w owns q rows q0+w*16..+15 (lane li = its q row).
// K/V LDS: linear [64 rows][128 B], content XOR-swizzled via pre-swizzled GLOBAL source
// (byte ^= (row&7)<<4); every read applies the same XOR (rule: both-sides-or-neither).
__global__ __launch_bounds__(512) void attn_kernel(const bf16* __restrict__ qkv,
                                                   const bf16* __restrict__ Vt,
                                                   bf16* __restrict__ Y) {
  __shared__ bf16 Ks[2][64 * 64];
  __shared__ bf16 Vs[2][64 * 64];
  __shared__ bf16 Ps[8 * 16 * 72];   // per-wave [16 q][72] padded relayout buffer

  const int tid = threadIdx.x;
  const int wid = tid >> 6, lane = tid & 63;
  const int grp = lane >> 4, li = lane & 15;
  const int QT = gridDim.x - 1 - blockIdx.x;   // heavy blocks first
  const int bh = blockIdx.y;
  const int b = bh >> 4, h = bh & 15;
  const int q0 = QT * 128;
  const int wq0 = q0 + wid * 16;               // wave's first q row
  const int qi = wq0 + li;                     // this lane's q row
  const float slope2 = exp2f(-0.5f * (float)(h + 1)) * LOG2E;

  bf16* Pw = Ps + wid * (16 * 72);

  // Q fragments (B-operand: row=li<->q, k=d), pre-scaled by 1/8 (exact in bf16)
  bf16x8 qf[2];
  {
    const bf16* qrow = qkv + (size_t)(b * T_ + qi) * QKV_S + h * D_;
    qf[0] = *reinterpret_cast<const bf16x8*>(qrow + grp * 8);
    qf[1] = *reinterpret_cast<const bf16x8*>(qrow + 32 + grp * 8);
#pragma unroll
    for (int c = 0; c < 2; ++c)
#pragma unroll
      for (int j = 0; j < 8; ++j)
        qf[c][j] = (bf16)((float)qf[c][j] * 0.125f);
  }

  // per-lane ALiBi precompute (log2 domain): bias2 = slope2*(kv - qi)
  //   = [slope2*kv0 - slope2*qi] + off[n][j],  off[n][j] = slope2*(n*16+grp*4+j)
  float off[4][4];
#pragma unroll
  for (int n = 0; n < 4; ++n)
#pragma unroll
    for (int j = 0; j < 4; ++j)
      off[n][j] = slope2 * (float)(n * 16 + grp * 4 + j);
  const float bb = -slope2 * (float)qi;

  f32x4 oacc[4] = {};      // O^T: [d = nd*16+grp*4+j][q = li]
  float mrun = -1e30f, lrun = 0.f;

  const bf16* Kbase = qkv + (size_t)b * T_ * QKV_S + C_ + (size_t)h * D_;
  const bf16* Vbase = Vt + (size_t)bh * D_ * T_;

  // staging geometry: 512 threads x 16B = one 64x128B tile; thread t -> row t>>3, bytecol (t&7)*16
  const int strow = tid >> 3;
  const int stswz = ((tid & 7) * 16) ^ ((strow & 7) << 4);  // inverse-swizzled source byte col
  const int rsw = (li & 7) << 4;                            // read byte XOR ((row&7)<<4)

  auto stage = [&](int kv0, int bufi) __attribute__((always_inline)) {
    const bf16* gk = Kbase + (size_t)(kv0 + strow) * QKV_S + (stswz >> 1);
    const bf16* gv = Vbase + (size_t)strow * T_ + kv0 + (stswz >> 1);
    __builtin_amdgcn_global_load_lds((__attribute__((address_space(1))) void*)gk,
                                     (__attribute__((address_space(3))) void*)(&Ks[bufi][wid * 512]), 16, 0, 0);
    __builtin_amdgcn_global_load_lds((__attribute__((address_space(1))) void*)gv,
                                     (__attribute__((address_space(3))) void*)(&Vs[bufi][wid * 512]), 16, 0, 0);
  };

  auto compute = [&](int kv0, int bufi, bool masked) __attribute__((always_inline)) {
    const char* Kb = (const char*)&Ks[bufi][0];
    const char* Vb = (const char*)&Vs[bufi][0];

    // S^T = K @ Q^T : K frags are A-operand rows (kv = n*16+li), k = d
    f32x4 s[4] = {};
    __builtin_amdgcn_s_setprio(1);
#pragma unroll
    for (int n = 0; n < 4; ++n) {
      const char* kr = Kb + (n * 16 + li) * 128;
      bf16x8 kf0 = *reinterpret_cast<const bf16x8*>(kr + ((grp * 16) ^ rsw));
      bf16x8 kf1 = *reinterpret_cast<const bf16x8*>(kr + ((64 + grp * 16) ^ rsw));
      s[n] = __builtin_amdgcn_mfma_f32_16x16x32_bf16(kf0, qf[0], s[n], 0, 0, 0);
      s[n] = __builtin_amdgcn_mfma_f32_16x16x32_bf16(kf1, qf[1], s[n], 0, 0, 0);
    }
    __builtin_amdgcn_s_setprio(0);

    // lane-local log2-domain softmax over 16 kv regs; 2 shuffles per reduce
    const float base = fmaf(slope2, (float)kv0, bb);
    float p[4][4];
    float rm = -1e30f;
#pragma unroll
    for (int n = 0; n < 4; ++n)
#pragma unroll
      for (int j = 0; j < 4; ++j) {
        float sv = fmaf(s[n][j], LOG2E, base + off[n][j]);
        if (masked) {
          const int kv = kv0 + n * 16 + grp * 4 + j;
          sv = (kv <= qi) ? sv : -1e30f;
        }
        p[n][j] = sv;
        rm = fmaxf(rm, sv);
      }
    rm = fmaxf(rm, __shfl_xor(rm, 16, 64));
    rm = fmaxf(rm, __shfl_xor(rm, 32, 64));
    const float mnew = fmaxf(mrun, rm);
    const float alpha = exp2f(mrun - mnew);
    mrun = mnew;
    float rs = 0.f;
#pragma unroll
    for (int n = 0; n < 4; ++n)
#pragma unroll
      for (int j = 0; j < 4; ++j) {
        float e = exp2f(p[n][j] - mnew);
        p[n][j] = e;
        rs += e;
      }
    rs += __shfl_xor(rs, 16, 64);
    rs += __shfl_xor(rs, 32, 64);
    lrun = lrun * alpha + rs;
#pragma unroll
    for (int nd = 0; nd < 4; ++nd)
#pragma unroll
      for (int j = 0; j < 4; ++j)
        oacc[nd][j] *= alpha;

    // P relayout through per-wave LDS: lane li owns q-row; B-operand needs row=q=li, k=kv
#pragma unroll
    for (int n = 0; n < 4; ++n) {
      bf16x4 p4;
#pragma unroll
      for (int j = 0; j < 4; ++j) p4[j] = (bf16)p[n][j];
      *reinterpret_cast<bf16x4*>(Pw + li * 72 + n * 16 + grp * 4) = p4;
    }
    asm volatile("s_waitcnt lgkmcnt(0)" ::: "memory");
    __builtin_amdgcn_sched_barrier(0);

    // O^T += Vt-tile @ P^T : V frags are A-operand rows (d = nd*16+li), k = kv
    __builtin_amdgcn_s_setprio(1);
#pragma unroll
    for (int kc = 0; kc < 2; ++kc) {
      bf16x8 pb = *reinterpret_cast<const bf16x8*>(Pw + li * 72 + kc * 32 + grp * 8);
#pragma unroll
      for (int nd = 0; nd < 4; ++nd) {
        const char* vrp = Vb + (nd * 16 + li) * 128;
        bf16x8 vf = *reinterpret_cast<const bf16x8*>(vrp + ((kc * 64 + grp * 16) ^ rsw));
        oacc[nd] = __builtin_amdgcn_mfma_f32_16x16x32_bf16(vf, pb, oacc[nd], 0, 0, 0);
      }
    }
    __builtin_amdgcn_s_setprio(0);
  };

  const int nt = 2 * QT + 2;
  stage(0, 0);
  __syncthreads();
  int cur = 0;
  for (int t = 0; t < nt; ++t) {
    const int kv0 = t * 64;
    if (t + 1 < nt) stage((t + 1) * 64, cur ^ 1);
    if (kv0 <= wq0) compute(kv0, cur, kv0 + 64 > wq0);   // wave-uniform skip past diagonal
    __syncthreads();   // vmcnt+lgkm drain + barrier: next tile staged, buffers safe to flip
    cur ^= 1;
  }

  // epilogue: O^T/l -> transpose via Pw -> Y rows (coalesced 16B)
  const float rinv = 1.f / lrun;
#pragma unroll
  for (int nd = 0; nd < 4; ++nd) {
    bf16x4 o4;
#pragma unroll
    for (int j = 0; j < 4; ++j) o4[j] = (bf16)(oacc[nd][j] * rinv);
    *reinterpret_cast<bf16x4*>(Pw + li * 72 + nd * 16 + grp * 4) = o4;
  }
  asm volatile("s_waitcnt lgkmcnt(0)" ::: "memory");
  __builtin_amdgcn_sched_barrier(0);
  {
    bf16* yrow = Y + (size_t)(b * T_ + qi) * C_ + h * D_;
#pragma unroll
    for (int c = 0; c < 2; ++c) {
      bf16x8 y8 = *reinterpret_cast<const bf16x8*>(Pw + li * 72 + (c * 4 + grp) * 8);
      *reinterpret_cast<bf16x8*>(yrow + (c * 4 + grp) * 8) = y8;
    }
  }
}

// ---------------------------------------------------------------- launch
extern "C" void kernel_launch(void* const* d_in, const int* in_sizes, int n_in,
                              void* d_out, int out_size, void* d_ws, size_t ws_size,
                              hipStream_t stream) {
  const float* x  = (const float*)d_in[0];
  const float* Wq = (const float*)d_in[1];
  const float* bq = (const float*)d_in[2];
  const float* Wk = (const float*)d_in[3];
  const float* bk = (const float*)d_in[4];
  const float* Wv = (const float*)d_in[5];
  const float* bv = (const float*)d_in[6];
  const float* Wo = (const float*)d_in[7];
  const float* bo = (const float*)d_in[8];
  float* out = (float*)d_out;

  char* ws = (char*)d_ws;
  bf16* xb    = (bf16*)ws; ws += (size_t)BT_ * C_ * 2;          // 8 MB (reused as yb)
  bf16* wqkvb = (bf16*)ws; ws += (size_t)3 * C_ * C_ * 2;       // 6 MB
  bf16* wob   = (bf16*)ws; ws += (size_t)C_ * C_ * 2;           // 2 MB
  bf16* qkvb  = (bf16*)ws; ws += (size_t)BT_ * QKV_S * 2;       // 24 MB (V third unused)
  bf16* vtb   = (bf16*)ws; ws += (size_t)B_ * H_ * D_ * T_ * 2; // 8 MB
  float* bqkv = (float*)ws; ws += (size_t)3 * C_ * 4;           // 12 KB
  bf16* yb    = xb;  // x dead after QKV GEMM

  hipMemcpyAsync(bqkv,          bq, C_ * 4, hipMemcpyDeviceToDevice, stream);
  hipMemcpyAsync(bqkv + C_,     bk, C_ * 4, hipMemcpyDeviceToDevice, stream);
  hipMemcpyAsync(bqkv + 2 * C_, bv, C_ * 4, hipMemcpyDeviceToDevice, stream);

  // fused cast: x + all 4 weights in one launch
  {
    const int total4 = (BT_ * C_ + 4 * C_ * C_) / 4;   // 2097152
    cast_all<<<dim3(total4 / 256), dim3(256), 0, stream>>>(x, Wq, Wk, Wv, Wo, xb, wqkvb, wob);
  }

  // fused QKV projection: [BT,1024] @ [3072,1024]^T -> [BT,3072]; V part written transposed to vtb
  gemm_bt<bf16, true><<<dim3(QKV_S / 128, BT_ / 128), dim3(256), 0, stream>>>(
      xb, wqkvb, bqkv, qkvb, vtb, BT_, QKV_S, C_);

  attn_kernel<<<dim3(T_ / 128, B_ * H_), dim3(512), 0, stream>>>(qkvb, vtb, yb);

  gemm_bt<float, false><<<dim3(C_ / 128, BT_ / 128), dim3(256), 0, stream>>>(
      yb, wob, bo, out, nullptr, BT_, C_, C_);
}

// Round 7
// 226.070 us; speedup vs baseline: 1.9292x; 1.0556x over previous
//
#include <hip/hip_runtime.h>
#include <hip/hip_bf16.h>
#include <cstdint>
#include <cstddef>

#define B_ 2
#define T_ 2048
#define C_ 1024
#define H_ 16
#define D_ 64
#define BT_ (B_*T_)
#define QKV_S 3072

typedef __bf16 bf16;
typedef __bf16 bf16x4 __attribute__((ext_vector_type(4)));
typedef __bf16 bf16x8 __attribute__((ext_vector_type(8)));
typedef float f32x4 __attribute__((ext_vector_type(4)));

// ---------------------------------------------------------------- fused cast f32->bf16 (+ bias concat)
__global__ __launch_bounds__(256) void cast_all(const float* __restrict__ x,
                                                const float* __restrict__ wq,
                                                const float* __restrict__ wk,
                                                const float* __restrict__ wv,
                                                const float* __restrict__ wo,
                                                const float* __restrict__ bq,
                                                const float* __restrict__ bk,
                                                const float* __restrict__ bv,
                                                bf16* __restrict__ xb,
                                                bf16* __restrict__ wqkvb,
                                                bf16* __restrict__ wob,
                                                float* __restrict__ bqkv) {
  const int X4 = (BT_ * C_) / 4;     // 1048576
  const int W4 = (C_ * C_) / 4;      // 262144
  int i = blockIdx.x * blockDim.x + threadIdx.x;
  if (i >= X4 + 4 * W4 + 768) return;
  if (i >= X4 + 4 * W4) {
    // bias copy: 3 x 1024 f32 -> bqkv
    int idx = i - (X4 + 4 * W4);        // 0..767 float4s
    int w = idx >> 8, off = idx & 255;
    const float* src = (w == 0) ? bq : (w == 1) ? bk : bv;
    reinterpret_cast<float4*>(bqkv + w * C_)[off] = reinterpret_cast<const float4*>(src)[off];
    return;
  }
  const float* src;
  bf16* dst;
  int off;
  if (i < X4) {
    src = x; dst = xb; off = i;
  } else {
    int k = i - X4;
    int w = k >> 18;        // /W4
    off = k & (W4 - 1);
    src = (w == 0) ? wq : (w == 1) ? wk : (w == 2) ? wv : wo;
    dst = (w < 3) ? (wqkvb + (size_t)w * C_ * C_) : wob;
  }
  float4 v = reinterpret_cast<const float4*>(src)[off];
  bf16x4 o;
  o[0] = (bf16)v.x; o[1] = (bf16)v.y; o[2] = (bf16)v.z; o[3] = (bf16)v.w;
  *reinterpret_cast<bf16x4*>(dst + (size_t)off * 4) = o;
}

// ---------------------------------------------------------------- GEMM: C = A @ B^T + bias
// A [M,K] bf16 row-major, Bm [N,K] bf16 row-major, bias [N] f32.
// 128x128 tile, BK=32, 256 threads = 4 waves (2x2), each wave 64x64 = 4x4 frags.
// 3-buffer depth-2 pipeline, counted vmcnt, ONE raw barrier per K-step:
//   iter t: { s_waitcnt vmcnt(4); s_barrier; stage(t+2, (t+2)%3); compute(t, t%3) }
// stage(t+2) overwrites the buffer read at compute(t-1) -> all waves passed this
// iter's barrier after their compute(t-1): race-free with a single barrier.
template<typename OutT, bool FUSE_VT>
__global__ __launch_bounds__(256) void gemm_bt(const bf16* __restrict__ A,
                                               const bf16* __restrict__ Bm,
                                               const float* __restrict__ bias,
                                               OutT* __restrict__ Cout,
                                               bf16* __restrict__ VtOut,
                                               int M, int N, int K) {
  __shared__ bf16 As[3][128 * 32];
  __shared__ bf16 Bs[3][128 * 32];
  const int tid = threadIdx.x;
  const int wid = tid >> 6, lane = tid & 63;
  const int grp = lane >> 4, li = lane & 15;
  const int wr = wid >> 1, wc = wid & 1;
  const int m0 = blockIdx.y * 128, n0 = blockIdx.x * 128;

  f32x4 acc[4][4] = {};

  const int srow = lane >> 2;         // 0..15
  const int scol = (lane & 3) * 8;    // 0,8,16,24

  auto stage = [&](int k0, int bufi) __attribute__((always_inline)) {
#pragma unroll
    for (int p = 0; p < 2; ++p) {
      const int rbase = (p * 4 + wid) * 16;
      const bf16* ga = A + (size_t)(m0 + rbase + srow) * K + (k0 + scol);
      const bf16* gb = Bm + (size_t)(n0 + rbase + srow) * K + (k0 + scol);
      __builtin_amdgcn_global_load_lds((__attribute__((address_space(1))) void*)ga,
                                       (__attribute__((address_space(3))) void*)(&As[bufi][(p * 4 + wid) * 512]), 16, 0, 0);
      __builtin_amdgcn_global_load_lds((__attribute__((address_space(1))) void*)gb,
                                       (__attribute__((address_space(3))) void*)(&Bs[bufi][(p * 4 + wid) * 512]), 16, 0, 0);
    }
  };

  const int nt = K >> 5;
  stage(0, 0);
  if (nt > 1) stage(32, 1);
  int r = 0;                          // buffer holding tile t
  for (int t = 0; t < nt; ++t) {
    if (t + 1 < nt) asm volatile("s_waitcnt vmcnt(4)\ns_barrier" ::: "memory");
    else            asm volatile("s_waitcnt vmcnt(0)\ns_barrier" ::: "memory");
    if (t + 2 < nt) stage((t + 2) * 32, (r == 0) ? 2 : r - 1);   // (r+2)%3

    bf16x8 af[4], bfr[4];
#pragma unroll
    for (int m = 0; m < 4; ++m)
      af[m] = *reinterpret_cast<const bf16x8*>(&As[r][(wr * 64 + m * 16 + li) * 32 + grp * 8]);
#pragma unroll
    for (int n = 0; n < 4; ++n)
      bfr[n] = *reinterpret_cast<const bf16x8*>(&Bs[r][(wc * 64 + n * 16 + li) * 32 + grp * 8]);
#pragma unroll
    for (int m = 0; m < 4; ++m)
#pragma unroll
      for (int n = 0; n < 4; ++n)
        acc[m][n] = __builtin_amdgcn_mfma_f32_16x16x32_bf16(af[m], bfr[n], acc[m][n], 0, 0, 0);

    r = (r == 2) ? 0 : r + 1;
  }

  float bcol[4];
#pragma unroll
  for (int n = 0; n < 4; ++n) bcol[n] = bias[n0 + wc * 64 + n * 16 + li];

  if (FUSE_VT && n0 >= 2 * C_) {
    // V block: write transposed to Vt[b*16+h][d][t]  (col-2048 = h*64+d; row = b*2048+t)
#pragma unroll
    for (int m = 0; m < 4; ++m) {
      const int row0 = m0 + wr * 64 + m * 16 + grp * 4;   // 4-aligned
      const int b = row0 >> 11, t = row0 & (T_ - 1);
#pragma unroll
      for (int n = 0; n < 4; ++n) {
        const int hd = (n0 - 2 * C_) + wc * 64 + n * 16 + li;
        bf16x4 o4;
#pragma unroll
        for (int j = 0; j < 4; ++j) o4[j] = (bf16)(acc[m][n][j] + bcol[n]);
        *reinterpret_cast<bf16x4*>(VtOut + ((size_t)(b * C_ + hd)) * T_ + t) = o4;
      }
    }
  } else {
#pragma unroll
    for (int m = 0; m < 4; ++m) {
#pragma unroll
      for (int n = 0; n < 4; ++n) {
        const int col = n0 + wc * 64 + n * 16 + li;
#pragma unroll
        for (int j = 0; j < 4; ++j) {
          const int row = m0 + wr * 64 + m * 16 + grp * 4 + j;
          float v = acc[m][n][j] + bcol[n];
          Cout[(size_t)row * N + col] = (OutT)v;
        }
      }
    }
  }
}

// ---------------------------------------------------------------- flash attention w/ ALiBi
// Swapped-operand (S^T = K@Q^T) flash attention; 8 waves x 16 q-rows = QBLK 128.
// kv tiles iterated in REVERSE (diagonal first): ALiBi decays away from the diagonal,
// so the running max is set by the first computed tile and defer-max (T13) skips
// nearly every O-rescale. 3-buffer depth-2 pipeline with counted vmcnt + one raw
// barrier per tile (same scheme as gemm_bt).
// qkv: [B*T,3072] bf16 (q at h*64, k at 1024+h*64). Vt: [B*H,64,T] bf16. Y: [B*T,1024] bf16.
// Grid (T/128, B*H), block 512. Wave w owns q rows q0+w*16..+15 (lane li = its q row).
// K/V LDS: linear [64 rows][128 B], content XOR-swizzled via pre-swizzled GLOBAL source
// (byte ^= (row&7)<<4); every read applies the same XOR (rule: both-sides-or-neither).
__global__ __launch_bounds__(512) void attn_kernel(const bf16* __restrict__ qkv,
                                                   const bf16* __restrict__ Vt,
                                                   bf16* __restrict__ Y) {
  __shared__ bf16 Ks[3][64 * 64];
  __shared__ bf16 Vs[3][64 * 64];
  __shared__ bf16 Ps[8 * 16 * 72];   // per-wave [16 q][72] padded relayout buffer

  const int tid = threadIdx.x;
  const int wid = tid >> 6, lane = tid & 63;
  const int grp = lane >> 4, li = lane & 15;
  const int QT = gridDim.x - 1 - blockIdx.x;   // heavy blocks first
  const int bh = blockIdx.y;
  const int b = bh >> 4, h = bh & 15;
  const int q0 = QT * 128;
  const int wq0 = q0 + wid * 16;               // wave's first q row
  const int qi = wq0 + li;                     // this lane's q row
  const float slope = exp2f(-0.5f * (float)(h + 1));

  bf16* Pw = Ps + wid * (16 * 72);

  // Q fragments (B-operand: row=li<->q, k=d), pre-scaled by 1/8 (exact in bf16)
  bf16x8 qf[2];
  {
    const bf16* qrow = qkv + (size_t)(b * T_ + qi) * QKV_S + h * D_;
    qf[0] = *reinterpret_cast<const bf16x8*>(qrow + grp * 8);
    qf[1] = *reinterpret_cast<const bf16x8*>(qrow + 32 + grp * 8);
#pragma unroll
    for (int c = 0; c < 2; ++c)
#pragma unroll
      for (int j = 0; j < 8; ++j)
        qf[c][j] = (bf16)((float)qf[c][j] * 0.125f);
  }

  f32x4 oacc[4] = {};      // O^T: [d = nd*16+grp*4+j][q = li]
  float mrun = -1e30f, lrun = 0.f;

  const bf16* Kbase = qkv + (size_t)b * T_ * QKV_S + C_ + (size_t)h * D_;
  const bf16* Vbase = Vt + (size_t)bh * D_ * T_;

  // staging geometry: 512 threads x 16B = one 64x128B tile; thread t -> row t>>3, bytecol (t&7)*16
  const int strow = tid >> 3;
  const int stswz = ((tid & 7) * 16) ^ ((strow & 7) << 4);  // inverse-swizzled source byte col
  const int rsw = (li & 7) << 4;                            // read byte XOR ((row&7)<<4)

  auto stage = [&](int kv0, int bufi) __attribute__((always_inline)) {
    const bf16* gk = Kbase + (size_t)(kv0 + strow) * QKV_S + (stswz >> 1);
    const bf16* gv = Vbase + (size_t)strow * T_ + kv0 + (stswz >> 1);
    __builtin_amdgcn_global_load_lds((__attribute__((address_space(1))) void*)gk,
                                     (__attribute__((address_space(3))) void*)(&Ks[bufi][wid * 512]), 16, 0, 0);
    __builtin_amdgcn_global_load_lds((__attribute__((address_space(1))) void*)gv,
                                     (__attribute__((address_space(3))) void*)(&Vs[bufi][wid * 512]), 16, 0, 0);
  };

  auto compute = [&](int kv0, int bufi, bool masked) __attribute__((always_inline)) {
    const char* Kb = (const char*)&Ks[bufi][0];
    const char* Vb = (const char*)&Vs[bufi][0];

    // S^T = K @ Q^T : K frags are A-operand rows (kv = n*16+li), k = d
    f32x4 s[4] = {};
    __builtin_amdgcn_s_setprio(1);
#pragma unroll
    for (int n = 0; n < 4; ++n) {
      const char* kr = Kb + (n * 16 + li) * 128;
      bf16x8 kf0 = *reinterpret_cast<const bf16x8*>(kr + ((grp * 16) ^ rsw));
      bf16x8 kf1 = *reinterpret_cast<const bf16x8*>(kr + ((64 + grp * 16) ^ rsw));
      s[n] = __builtin_amdgcn_mfma_f32_16x16x32_bf16(kf0, qf[0], s[n], 0, 0, 0);
      s[n] = __builtin_amdgcn_mfma_f32_16x16x32_bf16(kf1, qf[1], s[n], 0, 0, 0);
    }
    __builtin_amdgcn_s_setprio(0);

    // lane-local softmax over 16 kv regs (kv = kv0 + n*16 + grp*4 + j); 2 shuffles per reduce
    float p[4][4];
    float rm = -1e30f;
#pragma unroll
    for (int n = 0; n < 4; ++n)
#pragma unroll
      for (int j = 0; j < 4; ++j) {
        const int kv = kv0 + n * 16 + grp * 4 + j;
        float sv = fmaf(-slope, (float)(qi - kv), s[n][j]);
        if (masked) sv = (kv <= qi) ? sv : -1e30f;
        p[n][j] = sv;
        rm = fmaxf(rm, sv);
      }
    rm = fmaxf(rm, __shfl_xor(rm, 16, 64));
    rm = fmaxf(rm, __shfl_xor(rm, 32, 64));
    // T13 defer-max: skip rescale unless the tile max beats running max by > 8
    if (!__all(rm - mrun <= 8.0f)) {
      const float mnew = fmaxf(mrun, rm);
      const float alpha = __expf(mrun - mnew);
      mrun = mnew;
      lrun *= alpha;
#pragma unroll
      for (int nd = 0; nd < 4; ++nd)
#pragma unroll
        for (int j = 0; j < 4; ++j)
          oacc[nd][j] *= alpha;
    }
    float rs = 0.f;
#pragma unroll
    for (int n = 0; n < 4; ++n)
#pragma unroll
      for (int j = 0; j < 4; ++j) {
        float e = __expf(p[n][j] - mrun);
        p[n][j] = e;
        rs += e;
      }
    rs += __shfl_xor(rs, 16, 64);
    rs += __shfl_xor(rs, 32, 64);
    lrun += rs;

    // P relayout through per-wave LDS: lane li owns q-row; B-operand needs row=q=li, k=kv
#pragma unroll
    for (int n = 0; n < 4; ++n) {
      bf16x4 p4;
#pragma unroll
      for (int j = 0; j < 4; ++j) p4[j] = (bf16)p[n][j];
      *reinterpret_cast<bf16x4*>(Pw + li * 72 + n * 16 + grp * 4) = p4;
    }
    asm volatile("s_waitcnt lgkmcnt(0)" ::: "memory");
    __builtin_amdgcn_sched_barrier(0);

    // O^T += Vt-tile @ P^T : V frags are A-operand rows (d = nd*16+li), k = kv
    __builtin_amdgcn_s_setprio(1);
#pragma unroll
    for (int kc = 0; kc < 2; ++kc) {
      bf16x8 pb = *reinterpret_cast<const bf16x8*>(Pw + li * 72 + kc * 32 + grp * 8);
#pragma unroll
      for (int nd = 0; nd < 4; ++nd) {
        const char* vrp = Vb + (nd * 16 + li) * 128;
        bf16x8 vf = *reinterpret_cast<const bf16x8*>(vrp + ((kc * 64 + grp * 16) ^ rsw));
        oacc[nd] = __builtin_amdgcn_mfma_f32_16x16x32_bf16(vf, pb, oacc[nd], 0, 0, 0);
      }
    }
    __builtin_amdgcn_s_setprio(0);
  };

  const int nt = 2 * QT + 2;
  // reversed tile order: tile index t -> kv0 = (nt-1-t)*64  (diagonal first)
  stage((nt - 1) * 64, 0);
  stage((nt - 2) * 64, 1);
  int r = 0;
  for (int t = 0; t < nt; ++t) {
    if (t + 1 < nt) asm volatile("s_waitcnt vmcnt(2)\ns_barrier" ::: "memory");
    else            asm volatile("s_waitcnt vmcnt(0)\ns_barrier" ::: "memory");
    if (t + 2 < nt) stage((nt - 3 - t) * 64, (r == 0) ? 2 : r - 1);   // (r+2)%3
    const int kv0 = (nt - 1 - t) * 64;
    if (kv0 <= wq0) compute(kv0, r, kv0 + 64 > wq0);   // wave-uniform skip above diagonal
    r = (r == 2) ? 0 : r + 1;
  }

  // epilogue: O^T/l -> transpose via Pw -> Y rows (coalesced 16B)
  const float rinv = 1.f / lrun;
#pragma unroll
  for (int nd = 0; nd < 4; ++nd) {
    bf16x4 o4;
#pragma unroll
    for (int j = 0; j < 4; ++j) o4[j] = (bf16)(oacc[nd][j] * rinv);
    *reinterpret_cast<bf16x4*>(Pw + li * 72 + nd * 16 + grp * 4) = o4;
  }
  asm volatile("s_waitcnt lgkmcnt(0)" ::: "memory");
  __builtin_amdgcn_sched_barrier(0);
  {
    bf16* yrow = Y + (size_t)(b * T_ + qi) * C_ + h * D_;
#pragma unroll
    for (int c = 0; c < 2; ++c) {
      bf16x8 y8 = *reinterpret_cast<const bf16x8*>(Pw + li * 72 + (c * 4 + grp) * 8);
      *reinterpret_cast<bf16x8*>(yrow + (c * 4 + grp) * 8) = y8;
    }
  }
}

// ---------------------------------------------------------------- launch
extern "C" void kernel_launch(void* const* d_in, const int* in_sizes, int n_in,
                              void* d_out, int out_size, void* d_ws, size_t ws_size,
                              hipStream_t stream) {
  const float* x  = (const float*)d_in[0];
  const float* Wq = (const float*)d_in[1];
  const float* bq = (const float*)d_in[2];
  const float* Wk = (const float*)d_in[3];
  const float* bk = (const float*)d_in[4];
  const float* Wv = (const float*)d_in[5];
  const float* bv = (const float*)d_in[6];
  const float* Wo = (const float*)d_in[7];
  const float* bo = (const float*)d_in[8];
  float* out = (float*)d_out;

  char* ws = (char*)d_ws;
  bf16* xb    = (bf16*)ws; ws += (size_t)BT_ * C_ * 2;          // 8 MB (reused as yb)
  bf16* wqkvb = (bf16*)ws; ws += (size_t)3 * C_ * C_ * 2;       // 6 MB
  bf16* wob   = (bf16*)ws; ws += (size_t)C_ * C_ * 2;           // 2 MB
  bf16* qkvb  = (bf16*)ws; ws += (size_t)BT_ * QKV_S * 2;       // 24 MB (V third unused)
  bf16* vtb   = (bf16*)ws; ws += (size_t)B_ * H_ * D_ * T_ * 2; // 8 MB
  float* bqkv = (float*)ws; ws += (size_t)3 * C_ * 4;           // 12 KB
  bf16* yb    = xb;  // x dead after QKV GEMM

  // fused cast: x + all 4 weights + bias concat in one launch
  {
    const int total = (BT_ * C_ + 4 * C_ * C_) / 4 + 768;
    cast_all<<<dim3((total + 255) / 256), dim3(256), 0, stream>>>(
        x, Wq, Wk, Wv, Wo, bq, bk, bv, xb, wqkvb, wob, bqkv);
  }

  // fused QKV projection: [BT,1024] @ [3072,1024]^T -> [BT,3072]; V part written transposed to vtb
  gemm_bt<bf16, true><<<dim3(QKV_S / 128, BT_ / 128), dim3(256), 0, stream>>>(
      xb, wqkvb, bqkv, qkvb, vtb, BT_, QKV_S, C_);

  attn_kernel<<<dim3(T_ / 128, B_ * H_), dim3(512), 0, stream>>>(qkvb, vtb, yb);

  gemm_bt<float, false><<<dim3(C_ / 128, BT_ / 128), dim3(256), 0, stream>>>(
      yb, wob, bo, out, nullptr, BT_, C_, C_);
}